// Round 3
// baseline (616.121 us; speedup 1.0000x reference)
//
#include <hip/hip_runtime.h>

// ---------------- ws layout (float indices) ----------------
#define WS_GT    0       // float gT[512][8]   (gamma .* Wpre, transposed [k][j])
#define WS_G     4096    // float G[8]         (sum_k gamma*W_j)
#define WS_K     4104    // float K[8]         (beta.W_j + bpre_j)
#define WS_NT    4112    // int   nTerms (padded to multiple of 8)
#define WS_TERMS 4128    // {float coef, uint zx} pairs, up to 688
#define MAX_RAW  672

// Pauli letters, 2 bits per qubit: 0=I, 1=X, 2=Z, 3=Y
// CNOT(c,t) conjugation tables (packed, index k = 4*wc + wt):
//   newc: I:[I,I,Z,Z] X:[X,X,Y,Y] Z:[Z,Z,I,I] Y:[Y,Y,X,X] -> 0x5F0AF5A0
//   newt: I:[I,X,Z,Y] X:[X,I,Y,Z] Z:[I,X,Z,Y] Y:[X,I,Y,Z] -> 0xB1E4B1E4
//   sign flip at (X,Z) k=6 and (Y,Y) k=15                 -> 0x8040
__device__ __forceinline__ void conj_cnot_step(unsigned &pat, int &sg, int c, int t) {
  unsigned wc = (pat >> (2 * c)) & 3u;
  unsigned wt = (pat >> (2 * t)) & 3u;
  unsigned k = 4u * wc + wt;
  unsigned nc = (0x5F0AF5A0u >> (2u * k)) & 3u;
  unsigned nt = (0xB1E4B1E4u >> (2u * k)) & 3u;
  if ((0x8040u >> k) & 1u) sg = -sg;
  pat &= ~((3u << (2 * c)) | (3u << (2 * t)));
  pat |= (nc << (2 * c)) | (nt << (2 * t));
}

// Conjugate by the ring CNOT(0,1)...CNOT(7,0) applied-to-state order:
// O <- C^dag O C processes gates in REVERSE: (7,0) first ... (0,1) last.
__device__ __forceinline__ void conj_ring(unsigned &pat, int &sg) {
#pragma unroll
  for (int g = 0; g < 8; ++g) {
    int c = 7 - g;
    int t = (c + 1) & 7;
    conj_cnot_step(pat, sg, c, t);
  }
}

__global__ void qsco_init_kernel(const float* __restrict__ ln_gamma,
                                 const float* __restrict__ ln_beta,
                                 const float* __restrict__ Wpre,   // [8,512]
                                 const float* __restrict__ bpre,   // [8]
                                 const float* __restrict__ theta,  // [8]
                                 const float* __restrict__ Wpost,  // [8]
                                 float* __restrict__ ws) {
  const int tid = threadIdx.x;

  // gT[k][j] = gamma[k] * Wpre[j][k]
  for (int i = tid; i < 4096; i += 256) {
    int k = i >> 3, j = i & 7;
    ws[WS_GT + i] = ln_gamma[k] * Wpre[j * 512 + k];
  }
  // G[j], K[j]
  if (tid < 8) {
    float gs = 0.f, ks = 0.f;
    for (int k = 0; k < 512; ++k) {
      float w = Wpre[tid * 512 + k];
      gs += ln_gamma[k] * w;
      ks += ln_beta[k] * w;
    }
    ws[WS_G + tid] = gs;
    ws[WS_K + tid] = ks + bpre[tid];
  }

  __shared__ unsigned basePat[16];
  __shared__ int baseSign[16];
  __shared__ int offs[17];
  __shared__ float tcoef[MAX_RAW];
  __shared__ unsigned tpat[MAX_RAW];
  __shared__ int firstIdx[MAX_RAW];

  if (tid == 0) {
    int off = 0;
    for (int o = 0; o < 16; ++o) {
      int i = o >> 1, p = o & 1;
      unsigned pat = (p ? 1u : 2u) << (2 * i);  // p=0: Z_i ; p=1: X_i
      int sg = 1;
      conj_ring(pat, sg);                        // through C2
      basePat[o] = pat;
      baseSign[o] = sg;
      int w = 0;
      for (int q = 0; q < 8; ++q)
        if ((pat >> (2 * q)) & 3u) ++w;
      offs[o] = off;
      off += (1 << w);
    }
    offs[16] = off;  // = 672
  }
  __syncthreads();

  // Expansion: slot = o*256 + b
  for (int slot = tid; slot < 16 * 256; slot += 256) {
    int o = slot >> 8, b = slot & 255;
    unsigned pat = basePat[o];
    int w = 0;
    for (int q = 0; q < 8; ++q)
      if ((pat >> (2 * q)) & 3u) ++w;
    if (b >= (1 << w)) continue;

    int i = o >> 1, p = o & 1;
    // layer-2 factor: Z_i -> cos(th_i) Z_i - sin(th_i) X_i
    float coef = Wpost[i] * (p ? -__sinf(theta[i]) : __cosf(theta[i]));
    coef *= (float)baseSign[o];

    unsigned newpat = 0;
    int j = 0;
#pragma unroll
    for (int q = 0; q < 8; ++q) {
      unsigned L = (pat >> (2 * q)) & 3u;
      if (L == 0u) continue;
      int bb = (b >> j) & 1;
      ++j;
      float c = __cosf(theta[q]), s = __sinf(theta[q]);
      if (L == 2u) {  // Z: b0 -> Z (cos), b1 -> X (-sin)
        if (bb) { newpat |= 1u << (2 * q); coef *= -s; }
        else    { newpat |= 2u << (2 * q); coef *= c; }
      } else {        // X: b0 -> X (cos), b1 -> Z (+sin)
        if (bb) { newpat |= 2u << (2 * q); coef *= s; }
        else    { newpat |= 1u << (2 * q); coef *= c; }
      }
    }
    int sg = 1;
    conj_ring(newpat, sg);                       // through C1
    coef *= (float)sg;

    bool hasY = false;
#pragma unroll
    for (int q = 0; q < 8; ++q)
      if (((newpat >> (2 * q)) & 3u) == 3u) hasY = true;

    int idx = offs[o] + b;
    if (hasY) {
      tcoef[idx] = 0.f;
      tpat[idx] = 0x80000000u | (unsigned)idx;   // unique sentinel, never matches
    } else {
      tcoef[idx] = coef;
      tpat[idx] = newpat;
    }
  }
  __syncthreads();

  const int total = offs[16];
  // dedupe phase A: find first occurrence of each pattern
  for (int idx = tid; idx < total; idx += 256) {
    unsigned myp = tpat[idx];
    int f = idx;
    for (int j2 = 0; j2 < idx; ++j2) {
      if (tpat[j2] == myp) { f = j2; break; }
    }
    firstIdx[idx] = f;
  }
  __syncthreads();
  // phase B: merge into canonical slot
  for (int idx = tid; idx < total; idx += 256) {
    int f = firstIdx[idx];
    if (f < idx) atomicAdd(&tcoef[f], tcoef[idx]);
  }
  __syncthreads();
  // compaction (thread 0, serial): keep canonical slots with |coef| >= 5e-6
  if (tid == 0) {
    int n = 0;
    for (int idx = 0; idx < total; ++idx) {
      if (firstIdx[idx] == idx && fabsf(tcoef[idx]) >= 5e-6f) {
        ws[WS_TERMS + 2 * n] = tcoef[idx];
        ws[WS_TERMS + 2 * n + 1] = __uint_as_float(tpat[idx]);
        ++n;
      }
    }
    int nPad = (n + 7) & ~7;
    for (int idx = n; idx < nPad; ++idx) {
      ws[WS_TERMS + 2 * idx] = 0.f;
      ws[WS_TERMS + 2 * idx + 1] = __uint_as_float(0u);
    }
    ((int*)ws)[WS_NT] = nPad;
  }
}

// ---------------- main kernel ----------------
// One wave per 64 rows, lane = row. E staged via wave-private LDS tile
// (stride 18 dwords: b64 reads land at 4-phase minimum, no extra conflicts).
#define TILE_STRIDE 18

__global__ __launch_bounds__(256, 2) void qsco_main_kernel(
    const float* __restrict__ E,
    const float* __restrict__ ws,
    const float* __restrict__ bpost,
    float* __restrict__ out,
    int nrows) {
  __shared__ float tile[4][64 * TILE_STRIDE];
  const int lane = threadIdx.x & 63;
  const int w = threadIdx.x >> 6;
  const int waveId = blockIdx.x * 4 + w;
  const int r0 = waveId * 64;
  if (r0 >= nrows) return;
  const int myRow = r0 + lane;
  float* tl = &tile[w][0];

  float s0 = 0.f, s1 = 0.f;
  float d[8];
#pragma unroll
  for (int j = 0; j < 8; ++j) d[j] = 0.f;

  const float* gT = ws + WS_GT;

  float4 va[4], vb[4];
  // stage-load helper (macro to keep everything in regs)
#define LOAD_CHUNK(dst, cbase)                                            \
  {                                                                       \
    _Pragma("unroll") for (int i = 0; i < 4; ++i) {                       \
      int f = lane + 64 * i;                                              \
      int rl = f >> 2, kq = f & 3;                                        \
      int rr = min(r0 + rl, nrows - 1);                                   \
      dst[i] = *(const float4*)(E + (size_t)rr * 512 + (cbase) + kq * 4); \
    }                                                                     \
  }
#define STORE_CHUNK(src)                                                  \
  {                                                                       \
    _Pragma("unroll") for (int i = 0; i < 4; ++i) {                       \
      int f = lane + 64 * i;                                              \
      int rl = f >> 2, kq = f & 3;                                        \
      int base = rl * TILE_STRIDE + kq * 4;                               \
      *(float2*)(tl + base) = make_float2(src[i].x, src[i].y);            \
      *(float2*)(tl + base + 2) = make_float2(src[i].z, src[i].w);        \
    }                                                                     \
  }
#define COMPUTE_CHUNK(cbase)                                              \
  {                                                                       \
    _Pragma("unroll") for (int kk = 0; kk < 16; kk += 2) {                \
      float2 e2 = *(const float2*)(tl + lane * TILE_STRIDE + kk);         \
      const float* gk = gT + ((cbase) + kk) * 8;                          \
      s0 += e2.x + e2.y;                                                  \
      s1 = fmaf(e2.x, e2.x, fmaf(e2.y, e2.y, s1));                        \
      _Pragma("unroll") for (int j = 0; j < 8; ++j)                       \
        d[j] = fmaf(e2.y, gk[8 + j], fmaf(e2.x, gk[j], d[j]));            \
    }                                                                     \
  }

  LOAD_CHUNK(va, 0)
#pragma unroll 1
  for (int cb = 0; cb < 512; cb += 32) {
    LOAD_CHUNK(vb, cb + 16)
    STORE_CHUNK(va)
    COMPUTE_CHUNK(cb)
    if (cb + 32 < 512) LOAD_CHUNK(va, cb + 32)
    STORE_CHUNK(vb)
    COMPUTE_CHUNK(cb + 16)
  }

  // LayerNorm + angles (all per-lane)
  const float mu = s0 * (1.0f / 512.0f);
  const float var = s1 * (1.0f / 512.0f) - mu * mu;
  const float rstd = rsqrtf(var + 1e-5f);

  const float* Gp = ws + WS_G;
  const float* Kp = ws + WS_K;
  float cA[8], sA[8];
#pragma unroll
  for (int j = 0; j < 8; ++j) {
    float ang = rstd * (d[j] - mu * Gp[j]) + Kp[j];
    cA[j] = __cosf(ang);
    sA[j] = __sinf(ang);
  }

  // Observable evaluation: logit = sum_t coef_t * prod_q m_q + b_post
  // m_q: I->1, X->sinA_q, Z->cosA_q
  const int nT = __builtin_amdgcn_readfirstlane(((const int*)ws)[WS_NT]);
  const float* tp = ws + WS_TERMS;
  float acc = bpost[0];
#pragma unroll 1
  for (int t = 0; t < nT; t += 8) {
#pragma unroll
    for (int u = 0; u < 8; ++u) {
      float coef = tp[2 * (t + u)];
      unsigned zx = __float_as_uint(tp[2 * (t + u) + 1]);
      float prod = coef;
#pragma unroll
      for (int q = 0; q < 8; ++q) {
        unsigned L = (zx >> (2 * q)) & 3u;
        float m = (L == 0u) ? 1.0f : ((L == 1u) ? sA[q] : cA[q]);
        prod *= m;
      }
      acc += prod;
    }
  }

  if (myRow < nrows) out[myRow] = acc;
#undef LOAD_CHUNK
#undef STORE_CHUNK
#undef COMPUTE_CHUNK
}

extern "C" void kernel_launch(void* const* d_in, const int* in_sizes, int n_in,
                              void* d_out, int out_size, void* d_ws, size_t ws_size,
                              hipStream_t stream) {
  const float* E        = (const float*)d_in[0];
  const float* ln_gamma = (const float*)d_in[1];
  const float* ln_beta  = (const float*)d_in[2];
  const float* Wpre     = (const float*)d_in[3];
  const float* bpre     = (const float*)d_in[4];
  const float* theta    = (const float*)d_in[5];
  const float* Wpost    = (const float*)d_in[6];
  const float* bpost    = (const float*)d_in[7];
  float* out = (float*)d_out;
  float* ws = (float*)d_ws;

  const int nrows = in_sizes[0] / 512;

  qsco_init_kernel<<<1, 256, 0, stream>>>(ln_gamma, ln_beta, Wpre, bpre, theta,
                                          Wpost, ws);

  const int blocks = (nrows + 255) / 256;
  qsco_main_kernel<<<blocks, 256, 0, stream>>>(E, ws, bpost, out, nrows);
}

// Round 4
// 438.330 us; speedup vs baseline: 1.4056x; 1.4056x over previous
//
#include <hip/hip_runtime.h>

// ---------------- ws layout (float indices) ----------------
#define WS_GT    0       // float gT[512][8]  (gamma .* Wpre, transposed [k][j])
#define WS_G     4096    // float G[8]
#define WS_K     4104    // float K[8]
#define WS_COEF  4112    // float coef[nU]  (<= 672)

// ================= compile-time Pauli-term tables =================
// Pauli letters, 2 bits/qubit: 0=I, 1=X, 2=Z, 3=Y
constexpr void conj_cnot_ce(unsigned &pat, int &sg, int c, int t) {
  unsigned wc = (pat >> (2 * c)) & 3u;
  unsigned wt = (pat >> (2 * t)) & 3u;
  unsigned k = 4u * wc + wt;
  unsigned nc = (0x5F0AF5A0u >> (2u * k)) & 3u;
  unsigned nt = (0xB1E4B1E4u >> (2u * k)) & 3u;
  if ((0x8040u >> k) & 1u) sg = -sg;
  pat &= ~((3u << (2 * c)) | (3u << (2 * t)));
  pat |= (nc << (2 * c)) | (nt << (2 * t));
}
constexpr void conj_ring_ce(unsigned &pat, int &sg) {
  for (int g = 0; g < 8; ++g) {
    int c = 7 - g, t = (c + 1) & 7;
    conj_cnot_ce(pat, sg, c, t);
  }
}

#define MAX_RAW 672
struct CT {
  int nU, nR;
  unsigned short upat[MAX_RAW];   // unique final patterns
  int ustart[MAX_RAW + 1];        // CSR into grouped raw list
  short rsign[MAX_RAW];
  unsigned char rwi[MAX_RAW];     // Wpost index
  unsigned short rcos[MAX_RAW];   // cos exponents, 2b/qubit
  unsigned short rsin[MAX_RAW];   // sin exponents, 2b/qubit
};

constexpr CT build_ct() {
  CT T{};
  unsigned short rpat[MAX_RAW] = {};
  short rsgn[MAX_RAW] = {};
  unsigned char rwi_[MAX_RAW] = {};
  unsigned short rc_[MAX_RAW] = {}, rs_[MAX_RAW] = {};
  int nraw = 0;
  for (int o = 0; o < 16; ++o) {
    const int i = o >> 1, p = o & 1;
    unsigned pat = (p ? 1u : 2u) << (2 * i);  // p=0: Z_i ; p=1: X_i
    int sg0 = 1;
    conj_ring_ce(pat, sg0);  // conj through C2 ring
    int w = 0;
    for (int q = 0; q < 8; ++q)
      if ((pat >> (2 * q)) & 3u) ++w;
    for (int b = 0; b < (1 << w); ++b) {
      int sign = sg0;
      unsigned ce = 0, se = 0;
      // layer-2 factor: Z_i -> cos(th_i) Z_i ; X_i -> -sin(th_i) X_i
      if (p == 0) ce += 1u << (2 * i);
      else { se += 1u << (2 * i); sign = -sign; }
      unsigned np = 0;
      int j = 0;
      for (int q = 0; q < 8; ++q) {
        unsigned L = (pat >> (2 * q)) & 3u;
        if (!L) continue;
        int bb = (b >> j) & 1;
        ++j;
        if (L == 2u) {  // Z: cos*Z  |  -sin*X
          if (bb) { np |= 1u << (2 * q); se += 1u << (2 * q); sign = -sign; }
          else    { np |= 2u << (2 * q); ce += 1u << (2 * q); }
        } else {        // X: cos*X  |  +sin*Z
          if (bb) { np |= 2u << (2 * q); se += 1u << (2 * q); }
          else    { np |= 1u << (2 * q); ce += 1u << (2 * q); }
        }
      }
      int sg2 = 1;
      conj_ring_ce(np, sg2);  // conj through C1 ring
      sign *= sg2;
      bool hasY = false;
      for (int q = 0; q < 8; ++q)
        if (((np >> (2 * q)) & 3u) == 3u) hasY = true;
      if (hasY) continue;  // <Y> = 0 exactly in a real product state
      rpat[nraw] = (unsigned short)np;
      rsgn[nraw] = (short)sign;
      rwi_[nraw] = (unsigned char)i;
      rc_[nraw] = (unsigned short)ce;
      rs_[nraw] = (unsigned short)se;
      ++nraw;
    }
  }
  // dedupe via direct map on 16-bit pattern
  int map_[65536];
  for (int x = 0; x < 65536; ++x) map_[x] = -1;
  int uid[MAX_RAW] = {};
  int cnt[MAX_RAW] = {};
  int nU = 0;
  for (int r = 0; r < nraw; ++r) {
    int pp = rpat[r];
    if (map_[pp] < 0) { map_[pp] = nU; T.upat[nU] = (unsigned short)pp; ++nU; }
    uid[r] = map_[pp];
    cnt[uid[r]]++;
  }
  T.ustart[0] = 0;
  for (int u = 0; u < nU; ++u) T.ustart[u + 1] = T.ustart[u] + cnt[u];
  int fill[MAX_RAW] = {};
  for (int u = 0; u < nU; ++u) fill[u] = T.ustart[u];
  for (int r = 0; r < nraw; ++r) {
    int pos = fill[uid[r]]++;
    T.rsign[pos] = rsgn[r];
    T.rwi[pos] = rwi_[r];
    T.rcos[pos] = rc_[r];
    T.rsin[pos] = rs_[r];
  }
  T.nU = nU;
  T.nR = nraw;
  return T;
}

static constexpr CT kT = build_ct();

// ================= init kernel (all parallel, ~us) =================
__global__ void qsco_init_kernel(const float* __restrict__ ln_gamma,
                                 const float* __restrict__ ln_beta,
                                 const float* __restrict__ Wpre,   // [8,512]
                                 const float* __restrict__ bpre,   // [8]
                                 const float* __restrict__ theta,  // [8]
                                 const float* __restrict__ Wpost,  // [8]
                                 float* __restrict__ ws) {
  const int tid = threadIdx.x;

  // gT[k][j] = gamma[k] * Wpre[j][k]
  for (int i = tid; i < 4096; i += 256) {
    int k = i >> 3, j = i & 7;
    ws[WS_GT + i] = ln_gamma[k] * Wpre[j * 512 + k];
  }
  // G[j], K[j]: 32 threads per j
  {
    const int j = tid >> 5, l = tid & 31;
    float gs = 0.f, ks = 0.f;
    for (int t = 0; t < 16; ++t) {
      int k = l * 16 + t;
      float w = Wpre[j * 512 + k];
      gs = fmaf(ln_gamma[k], w, gs);
      ks = fmaf(ln_beta[k], w, ks);
    }
    for (int m = 1; m <= 16; m <<= 1) {
      gs += __shfl_xor(gs, m, 64);
      ks += __shfl_xor(ks, m, 64);
    }
    if (l == 0) {
      ws[WS_G + j] = gs;
      ws[WS_K + j] = ks + bpre[j];
    }
  }
  // per-unique-term coefficients
  float cth[8], sth[8];
#pragma unroll
  for (int q = 0; q < 8; ++q) {
    cth[q] = __cosf(theta[q]);
    sth[q] = __sinf(theta[q]);
  }
  for (int u = tid; u < kT.nU; u += 256) {
    float sum = 0.f;
    for (int r = kT.ustart[u]; r < kT.ustart[u + 1]; ++r) {
      float c = (float)kT.rsign[r] * Wpost[kT.rwi[r]];
      unsigned ce = kT.rcos[r], se = kT.rsin[r];
#pragma unroll
      for (int q = 0; q < 8; ++q) {
        int e1 = (ce >> (2 * q)) & 3;
        int e2 = (se >> (2 * q)) & 3;
        if (e1 >= 1) c *= cth[q];
        if (e1 == 2) c *= cth[q];
        if (e2 >= 1) c *= sth[q];
        if (e2 == 2) c *= sth[q];
      }
      sum += c;
    }
    ws[WS_COEF + u] = sum;
  }
}

// ================= main kernel =================
// Row-per-lane (64 rows/wave). E staged global->regs->LDS (wave-private,
// no barriers; DS in-order per wave). 16-col chunks, 2 LDS buffers,
// global prefetch 2 chunks ahead. stride 18 pads bank conflicts to ~4-way.
#define TS 18

__global__ __launch_bounds__(256, 2) void qsco_main_kernel(
    const float* __restrict__ E,
    const float* __restrict__ ws,
    const float* __restrict__ bpost,
    float* __restrict__ out,
    int nrows) {
  __shared__ float tile[4][2][64 * TS];  // 36864 B
  const int lane = threadIdx.x & 63;
  const int w = threadIdx.x >> 6;
  const int waveId = blockIdx.x * 4 + w;
  const int r0 = waveId * 64;
  if (r0 >= nrows) return;
  const int myRow = r0 + lane;
  float* bufA = &tile[w][0][0];
  float* bufB = &tile[w][1][0];
  const float* gT = ws + WS_GT;

  float s0 = 0.f, s1 = 0.f;
  float d[8];
#pragma unroll
  for (int j = 0; j < 8; ++j) d[j] = 0.f;

  float4 va[4], vb[4];

#define LOADC(dst, cbase)                                                  \
  { _Pragma("unroll") for (int ii = 0; ii < 4; ++ii) {                     \
      int f = lane + 64 * ii;                                              \
      int rl = f >> 2, kq = f & 3;                                         \
      int rr = min(r0 + rl, nrows - 1);                                    \
      dst[ii] = *(const float4*)(E + (size_t)rr * 512 + (cbase) + kq * 4); \
  } }
#define STOREC(buf, src)                                                   \
  { _Pragma("unroll") for (int ii = 0; ii < 4; ++ii) {                     \
      int f = lane + 64 * ii;                                              \
      int rl = f >> 2, kq = f & 3;                                         \
      float* p = (buf) + rl * TS + kq * 4;                                 \
      *(float2*)(p) = make_float2(src[ii].x, src[ii].y);                   \
      *(float2*)(p + 2) = make_float2(src[ii].z, src[ii].w);               \
  } }
#define COMPUTEC(buf, cbase)                                               \
  { _Pragma("unroll") for (int kk = 0; kk < 16; kk += 2) {                 \
      float2 e2 = *(const float2*)((buf) + lane * TS + kk);                \
      const float* gk = gT + ((cbase) + kk) * 8;                           \
      s0 += e2.x + e2.y;                                                   \
      s1 = fmaf(e2.x, e2.x, fmaf(e2.y, e2.y, s1));                         \
      _Pragma("unroll") for (int j = 0; j < 8; ++j)                        \
        d[j] = fmaf(e2.y, gk[8 + j], fmaf(e2.x, gk[j], d[j]));             \
  } }

  LOADC(va, 0)
  STOREC(bufA, va)
  LOADC(va, 16)
#pragma unroll 1
  for (int cb = 0; cb < 512; cb += 32) {
    if (cb + 32 < 512) LOADC(vb, cb + 32)      // global -> regs, 2 ahead
    STOREC(bufB, va)                           // chunk cb+16 -> LDS
    COMPUTEC(bufA, cb)                         // compute chunk cb
    STOREC(bufA, vb)                           // chunk cb+32 -> LDS
    if (cb + 48 < 512) LOADC(va, cb + 48)
    COMPUTEC(bufB, cb + 16)                    // compute chunk cb+16
  }

  // LayerNorm + angles (all per-lane)
  const float mu = s0 * (1.0f / 512.0f);
  const float var = s1 * (1.0f / 512.0f) - mu * mu;
  const float rstd = rsqrtf(var + 1e-5f);

  const float* Gp = ws + WS_G;
  const float* Kp = ws + WS_K;
  float cA[8], sA[8];
#pragma unroll
  for (int j = 0; j < 8; ++j) {
    float ang = rstd * (d[j] - mu * Gp[j]) + Kp[j];
    cA[j] = __cosf(ang);
    sA[j] = __sinf(ang);
  }

  // Observable: compile-time-unrolled Pauli-term sum.
  // <X_q> = sinA_q, <Z_q> = cosA_q, <I> = 1; coef from ws (runtime).
  const float* cf = ws + WS_COEF;
  float acc0 = bpost[0], acc1 = 0.f, acc2 = 0.f, acc3 = 0.f;
#pragma unroll
  for (int u = 0; u < kT.nU; ++u) {
    const unsigned pat = kT.upat[u];  // folds to an immediate after unroll
    float prod = cf[u];
#pragma unroll
    for (int q = 0; q < 8; ++q) {
      const unsigned L = (pat >> (2 * q)) & 3u;
      if (L == 1u) prod *= sA[q];
      else if (L == 2u) prod *= cA[q];
    }
    if ((u & 3) == 0) acc0 += prod;
    else if ((u & 3) == 1) acc1 += prod;
    else if ((u & 3) == 2) acc2 += prod;
    else acc3 += prod;
  }
  const float v = (acc0 + acc1) + (acc2 + acc3);
  if (myRow < nrows) out[myRow] = v;

#undef LOADC
#undef STOREC
#undef COMPUTEC
}

extern "C" void kernel_launch(void* const* d_in, const int* in_sizes, int n_in,
                              void* d_out, int out_size, void* d_ws, size_t ws_size,
                              hipStream_t stream) {
  const float* E        = (const float*)d_in[0];
  const float* ln_gamma = (const float*)d_in[1];
  const float* ln_beta  = (const float*)d_in[2];
  const float* Wpre     = (const float*)d_in[3];
  const float* bpre     = (const float*)d_in[4];
  const float* theta    = (const float*)d_in[5];
  const float* Wpost    = (const float*)d_in[6];
  const float* bpost    = (const float*)d_in[7];
  float* out = (float*)d_out;
  float* ws = (float*)d_ws;

  const int nrows = in_sizes[0] / 512;

  qsco_init_kernel<<<1, 256, 0, stream>>>(ln_gamma, ln_beta, Wpre, bpre, theta,
                                          Wpost, ws);

  const int blocks = (nrows + 255) / 256;
  qsco_main_kernel<<<blocks, 256, 0, stream>>>(E, ws, bpost, out, nrows);
}